// Round 11
// baseline (163.586 us; speedup 1.0000x reference)
//
#include <hip/hip_runtime.h>

typedef float f32x4 __attribute__((ext_vector_type(4)));

// Problem constants (from reference setup_inputs)
constexpr int B  = 4;
constexpr int M  = 1088;
constexpr int HH = 32;
constexpr int D  = 128;
constexpr int F  = 128;
constexpr int C  = 512;

constexpr int SZ_YNUM = B * C * HH * D;   // 8388608
constexpr int SZ_YDEN = B * C * HH;       // 65536
constexpr int SZ_KVM  = B * M * HH * D;   // 17825792
constexpr int SZ_H    = B * HH * F * D;   // 2097152
constexpr int SZ_S    = B * HH * F;       // 16384

constexpr int OFF_YNUM = 0;
constexpr int OFF_YDEN = OFF_YNUM + SZ_YNUM;
constexpr int OFF_K    = OFF_YDEN + SZ_YDEN;
constexpr int OFF_V    = OFF_K + SZ_KVM;
constexpr int OFF_FK   = OFF_V + SZ_KVM;
constexpr int OFF_H    = OFF_FK + SZ_KVM;
constexpr int OFF_S    = OFF_H + SZ_H;

constexpr int INNER4      = HH * D / 4;           // 1024 f32x4 per (b,m) row
constexpr int ROWS_PER_CB = 4;                    // 64 KB per copy block
constexpr int COPY_BLOCKS = B * M / ROWS_PER_CB;  // 1088 (exact)
constexpr int EPARTS      = 4;                    // e-dimension split of hs
constexpr int HS_BLOCKS   = B * HH * 2 * EPARTS;  // 1024
constexpr int Y_BLOCKS    = B * HH * 8;           // 1024
constexpr int RED_BLOCKS  = 256;                  // H reduce blocks

__device__ __forceinline__ void ring_params(const int* wp_p, const int* valid_p,
                                            int& wp, int& num_excess, int& pos) {
    wp = *wp_p;
    int valid = *valid_p;
    if (valid + C <= M) {
        num_excess = 0;
        pos = (wp + valid) % M;
    } else {
        num_excess = valid + C - M;
        pos = (wp + num_excess) % M;
    }
}

// ---------------------------------------------------------------------------
// One copy block = ROWS_PER_CB (b,m)-rows of one (B,M,HH,128) tensor.
// ---------------------------------------------------------------------------
__device__ __forceinline__ void ring_copy_block(int cb, int tid,
                                                const f32x4* __restrict__ src,
                                                const f32x4* __restrict__ chk,
                                                f32x4* __restrict__ dst,
                                                int pos) {
    int bm0 = cb * ROWS_PER_CB;
#pragma unroll
    for (int r = 0; r < ROWS_PER_CB; ++r) {
        int bm = bm0 + r;
        int m = bm % M;
        int b = bm / M;
        int off = m - pos;
        if (off < 0) off += M;
        const f32x4* s = (off < C) ? &chk[(b * C + off) * INNER4]
                                   : &src[bm * INNER4];
        f32x4* d = &dst[bm * INNER4];
#pragma unroll
        for (int k = 0; k < INNER4 / 256; ++k)
            d[k * 256 + tid] = s[k * 256 + tid];
    }
}

// ---------------------------------------------------------------------------
// hs partial body: block bx in [0,1024) -> (epart, fhalf, bh).
// Computes partial sum_{e in chunk} fk (x) v over a 64(f) x 128(d) tile,
// writes PARTIAL to ws.  ESTEP=16, double LDS buffer (25 KB), depth-2
// register prefetch: load(t+2) issued during iter t, stored during iter t+1.
// ---------------------------------------------------------------------------
constexpr int ESTEP = 16;

__device__ void hs_partial_body(int bx,
                                const float* __restrict__ FKi,
                                const float* __restrict__ Vi,
                                float* __restrict__ wsH,
                                float* __restrict__ wsS,
                                int wp, int num_excess) {
    const int tid = threadIdx.x;
    const int epart = bx & (EPARTS - 1);
    int rest = bx >> 2;
    const int fhalf = rest & 1;
    const int bh = rest >> 1;
    const int h = bh & (HH - 1);
    const int b = bh >> 5;
    const int fbase = fhalf * 64;

    const int echunk = (num_excess + EPARTS * ESTEP - 1) / (EPARTS * ESTEP) * ESTEP;
    const int e_lo = epart * echunk;
    const int e_hi_raw = e_lo + echunk;
    const int e_hi = (e_hi_raw < num_excess) ? e_hi_raw : num_excess;

    __shared__ float  fk_s[2][ESTEP][64];   // 2 x 4 KB
    __shared__ f32x4  v_s[2][ESTEP][32];    // 2 x 8 KB
    __shared__ float  sred[4][64];          // 1 KB

    const int tf = tid >> 5;   // 0..7  (8 f-rows each)
    const int td = tid & 31;   // 0..31 (d quads)
    const int cq = tid & 63;   // fk column / s column
    const int qq = tid >> 6;   // quarter

    f32x4 acc[8];
#pragma unroll
    for (int i = 0; i < 8; ++i) acc[i] = (f32x4)0.f;
    float s_part = 0.f;

    float fkA[4], fkB[4];
    f32x4 vA[2],  vB[2];

    auto load_tile = [&](int e0, float* fk_r, f32x4* v_r) {
#pragma unroll
        for (int j = 0; j < 4; ++j) {
            int e = e0 + qq + 4 * j;
            int me = wp + e;
            if (me >= M) me -= M;
            if (me >= M) me -= M;
            float v = 0.f;
            if (e < e_hi) v = FKi[((b * M + me) * HH + h) * F + fbase + cq];
            fk_r[j] = v;
        }
#pragma unroll
        for (int j = 0; j < 2; ++j) {
            int e = e0 + tf + 8 * j;
            int me = wp + e;
            if (me >= M) me -= M;
            if (me >= M) me -= M;
            f32x4 v = (f32x4)0.f;
            if (e < e_hi) v = *(const f32x4*)&Vi[((b * M + me) * HH + h) * D + td * 4];
            v_r[j] = v;
        }
    };
    auto store_tile = [&](const float* fk_r, const f32x4* v_r, int buf) {
#pragma unroll
        for (int j = 0; j < 4; ++j) fk_s[buf][qq + 4 * j][cq] = fk_r[j];
#pragma unroll
        for (int j = 0; j < 2; ++j) v_s[buf][tf + 8 * j][td] = v_r[j];
    };
    auto compute = [&](int buf) {
#pragma unroll
        for (int ee = 0; ee < ESTEP; ++ee) {
            f32x4 fa = *(const f32x4*)&fk_s[buf][ee][tf * 8];
            f32x4 fb = *(const f32x4*)&fk_s[buf][ee][tf * 8 + 4];
            f32x4 vv = v_s[buf][ee][td];
            acc[0] += fa.x * vv; acc[1] += fa.y * vv;
            acc[2] += fa.z * vv; acc[3] += fa.w * vv;
            acc[4] += fb.x * vv; acc[5] += fb.y * vv;
            acc[6] += fb.z * vv; acc[7] += fb.w * vv;
        }
#pragma unroll
        for (int j = 0; j < 4; ++j) s_part += fk_s[buf][qq * 4 + j][cq];
    };

    if (e_lo < e_hi) {
        const int nt = (e_hi - e_lo + ESTEP - 1) / ESTEP;
        load_tile(e_lo, fkA, vA);
        if (nt > 1) load_tile(e_lo + ESTEP, fkB, vB);   // in flight across iter 0
        store_tile(fkA, vA, 0);
        for (int t = 0; t < nt; t += 2) {
            // even t: compute buf0; B -> buf1; A <- tile t+2
            __syncthreads();
            if (t + 1 < nt) store_tile(fkB, vB, 1);
            if (t + 2 < nt) load_tile(e_lo + (t + 2) * ESTEP, fkA, vA);
            compute(0);
            if (t + 1 >= nt) break;
            // odd t+1: compute buf1; A -> buf0; B <- tile t+3
            __syncthreads();
            if (t + 2 < nt) store_tile(fkA, vA, 0);
            if (t + 3 < nt) load_tile(e_lo + (t + 3) * ESTEP, fkB, vB);
            compute(1);
        }
    }

    // S partial
    sred[qq][cq] = s_part;
    __syncthreads();
    if (tid < 64) {
        wsS[epart * SZ_S + (b * HH + h) * F + fbase + tid] =
            sred[0][tid] + sred[1][tid] + sred[2][tid] + sred[3][tid];
    }

    // H partial
    float* wsHp = wsH + epart * SZ_H;
#pragma unroll
    for (int i = 0; i < 8; ++i) {
        int f = fbase + tf * 8 + i;
        int base = ((b * HH + h) * F + f) * D + td * 4;
        *(f32x4*)&wsHp[base] = acc[i];
    }
}

// ---------------------------------------------------------------------------
// y body: block bx in [0,1024). 64(c) x 128(d) tile, f-step 32.
// Reads final H_new / S_new directly (produced by the reduce kernel).
// ---------------------------------------------------------------------------
__device__ void compute_y_den_body(int bx,
                                   const float* __restrict__ fq,
                                   const float* __restrict__ Hn,
                                   const float* __restrict__ Sn,
                                   float* __restrict__ ynum,
                                   float* __restrict__ yden) {
    const int tid = threadIdx.x;
    int t0 = bx;
    const int ct = t0 & 7; t0 >>= 3;
    const int h = t0 & (HH - 1);
    const int b = t0 >> 5;
    const int c0 = ct * 64;
    const int bh = b * HH + h;

    __shared__ float  fq_s[32][65];   // [ee][c], padded
    __shared__ f32x4  h_s[32][32];    // [ee][d4]
    __shared__ float  S_s[128];
    __shared__ float  den_s[64][4];

    const int tc = tid >> 5;  // 0..7 (8 c-rows each)
    const int td = tid & 31;  // 0..31 (d quads)
    const int cq = tid & 63;
    const int qq = tid >> 6;

    if (tid < 128) S_s[tid] = Sn[bh * F + tid];

    f32x4 acc[8];
#pragma unroll
    for (int i = 0; i < 8; ++i) acc[i] = (f32x4)0.f;
    float den_part = 0.f;

    for (int f0 = 0; f0 < F; f0 += 32) {
#pragma unroll
        for (int r = 0; r < 8; ++r) {
            int idx = tid + r * 256;
            int cc = idx >> 5, ee = idx & 31;
            fq_s[ee][cc] = fq[((b * C + c0 + cc) * HH + h) * F + f0 + ee];
        }
#pragma unroll
        for (int r = 0; r < 4; ++r) {
            int idx = tid + r * 256;
            int row = idx >> 5, col = idx & 31;
            h_s[row][col] = *(const f32x4*)&Hn[(bh * F + f0 + row) * D + col * 4];
        }
        __syncthreads();
#pragma unroll
        for (int ee = 0; ee < 32; ++ee) {
            f32x4 hv = h_s[ee][td];
#pragma unroll
            for (int i = 0; i < 8; ++i) {
                float q = fq_s[ee][tc * 8 + i];
                acc[i] += q * hv;
            }
        }
#pragma unroll
        for (int j = 0; j < 8; ++j)
            den_part += fq_s[qq * 8 + j][cq] * S_s[f0 + qq * 8 + j];
        __syncthreads();
    }

    den_s[cq][qq] = den_part;
    __syncthreads();
    if (tid < 64)
        yden[(b * C + c0 + tid) * HH + h] =
            den_s[tid][0] + den_s[tid][1] + den_s[tid][2] + den_s[tid][3];

#pragma unroll
    for (int i = 0; i < 8; ++i) {
        int c = c0 + tc * 8 + i;
        int base = ((b * C + c) * HH + h) * D + td * 4;
        *(f32x4*)&ynum[base] = acc[i];
    }
}

// ---------------------------------------------------------------------------
// Kernel 1: hs partials (blocks 0..1023) + V copy + FK copy.
// ---------------------------------------------------------------------------
__global__ __launch_bounds__(256) void fused_hs_vfk(
        const float* __restrict__ FKi, const float* __restrict__ Vi,
        float* __restrict__ wsH,       float* __restrict__ wsS,
        const f32x4* __restrict__ V4,  const f32x4* __restrict__ vc,  f32x4* __restrict__ oV,
        const f32x4* __restrict__ FK4, const f32x4* __restrict__ fkc, f32x4* __restrict__ oFK,
        const int* __restrict__ wp_p,  const int* __restrict__ valid_p) {
    int wp, num_excess, pos;
    ring_params(wp_p, valid_p, wp, num_excess, pos);

    int bx = blockIdx.x;
    if (bx < HS_BLOCKS) {
        hs_partial_body(bx, FKi, Vi, wsH, wsS, wp, num_excess);
        return;
    }
    bx -= HS_BLOCKS;
    if (bx < COPY_BLOCKS) {
        ring_copy_block(bx, threadIdx.x, V4, vc, oV, pos);
        return;
    }
    bx -= COPY_BLOCKS;
    ring_copy_block(bx, threadIdx.x, FK4, fkc, oFK, pos);
}

// ---------------------------------------------------------------------------
// Kernel 2: H/S reduce (blocks 0..255: o_H = H_in + sum partials) + K copy.
// ---------------------------------------------------------------------------
__global__ __launch_bounds__(256) void fused_red_k(
        const float* __restrict__ Hi,  const float* __restrict__ Si,
        const float* __restrict__ wsH, const float* __restrict__ wsS,
        float* __restrict__ Ho,        float* __restrict__ So,
        const f32x4* __restrict__ K4,  const f32x4* __restrict__ kc,
        f32x4* __restrict__ oK,
        const int* __restrict__ wp_p,  const int* __restrict__ valid_p) {
    int wp, num_excess, pos;
    ring_params(wp_p, valid_p, wp, num_excess, pos);

    int bx = blockIdx.x;
    const int tid = threadIdx.x;
    if (bx < RED_BLOCKS) {
        constexpr int H4 = SZ_H / 4;            // f32x4 count
        const f32x4* h4 = (const f32x4*)Hi;
        const f32x4* w4 = (const f32x4*)wsH;
        f32x4* o4 = (f32x4*)Ho;
        int base = bx * (H4 / RED_BLOCKS) + tid;  // 2048 f32x4 per block
#pragma unroll
        for (int r = 0; r < H4 / RED_BLOCKS / 256; ++r) {  // 8
            int i = base + r * 256;
            f32x4 v = h4[i];
            v += w4[0 * H4 + i];
            v += w4[1 * H4 + i];
            v += w4[2 * H4 + i];
            v += w4[3 * H4 + i];
            o4[i] = v;
        }
        if (bx < SZ_S / 256) {                   // 64 blocks cover S
            int si = bx * 256 + tid;
            So[si] = Si[si] + wsS[si] + wsS[SZ_S + si]
                   + wsS[2 * SZ_S + si] + wsS[3 * SZ_S + si];
        }
        return;
    }
    bx -= RED_BLOCKS;
    ring_copy_block(bx, tid, K4, kc, oK, pos);
}

// ---------------------------------------------------------------------------
// Kernel 3: y only (reads final H/S from d_out).
// ---------------------------------------------------------------------------
__global__ __launch_bounds__(256) void y_kernel(
        const float* __restrict__ fq, const float* __restrict__ Hn,
        const float* __restrict__ Sn,
        float* __restrict__ ynum,     float* __restrict__ yden) {
    compute_y_den_body(blockIdx.x, fq, Hn, Sn, ynum, yden);
}

// ---------------------------------------------------------------------------
extern "C" void kernel_launch(void* const* d_in, const int* in_sizes, int n_in,
                              void* d_out, int out_size, void* d_ws, size_t ws_size,
                              hipStream_t stream) {
    const float* K   = (const float*)d_in[0];
    const float* V   = (const float*)d_in[1];
    const float* FK  = (const float*)d_in[2];
    const float* H   = (const float*)d_in[3];
    const float* S   = (const float*)d_in[4];
    const float* k_c = (const float*)d_in[5];
    const float* v_c = (const float*)d_in[6];
    const float* fk_c= (const float*)d_in[7];
    const float* fq  = (const float*)d_in[8];
    const int* wp    = (const int*)d_in[9];
    const int* valid = (const int*)d_in[10];

    float* out = (float*)d_out;
    float* o_ynum = out + OFF_YNUM;
    float* o_yden = out + OFF_YDEN;
    float* o_K    = out + OFF_K;
    float* o_V    = out + OFF_V;
    float* o_FK   = out + OFF_FK;
    float* o_H    = out + OFF_H;
    float* o_S    = out + OFF_S;

    float* wsH = (float*)d_ws;              // 4 x SZ_H floats (33.5 MB)
    float* wsS = wsH + EPARTS * SZ_H;       // 4 x SZ_S floats (0.26 MB)

    // Kernel 1: hs partials overlapped with V, FK ring copies.
    fused_hs_vfk<<<HS_BLOCKS + 2 * COPY_BLOCKS, 256, 0, stream>>>(
        FK, V, wsH, wsS,
        (const f32x4*)V,  (const f32x4*)v_c,  (f32x4*)o_V,
        (const f32x4*)FK, (const f32x4*)fk_c, (f32x4*)o_FK,
        wp, valid);

    // Kernel 2: H/S reduce overlapped with K ring copy.
    fused_red_k<<<RED_BLOCKS + COPY_BLOCKS, 256, 0, stream>>>(
        H, S, wsH, wsS, o_H, o_S,
        (const f32x4*)K, (const f32x4*)k_c, (f32x4*)o_K,
        wp, valid);

    // Kernel 3: y_num / y_den.
    y_kernel<<<Y_BLOCKS, 256, 0, stream>>>(fq, o_H, o_S, o_ynum, o_yden);
}

// Round 12
// 146.958 us; speedup vs baseline: 1.1132x; 1.1132x over previous
//
#include <hip/hip_runtime.h>

typedef float f32x4 __attribute__((ext_vector_type(4)));

// Problem constants (from reference setup_inputs)
constexpr int B  = 4;
constexpr int M  = 1088;
constexpr int HH = 32;
constexpr int D  = 128;
constexpr int F  = 128;
constexpr int C  = 512;

constexpr int SZ_YNUM = B * C * HH * D;   // 8388608
constexpr int SZ_YDEN = B * C * HH;       // 65536
constexpr int SZ_KVM  = B * M * HH * D;   // 17825792
constexpr int SZ_H    = B * HH * F * D;   // 2097152
constexpr int SZ_S    = B * HH * F;       // 16384

constexpr int OFF_YNUM = 0;
constexpr int OFF_YDEN = OFF_YNUM + SZ_YNUM;
constexpr int OFF_K    = OFF_YDEN + SZ_YDEN;
constexpr int OFF_V    = OFF_K + SZ_KVM;
constexpr int OFF_FK   = OFF_V + SZ_KVM;
constexpr int OFF_H    = OFF_FK + SZ_KVM;
constexpr int OFF_S    = OFF_H + SZ_H;

constexpr int INNER4      = HH * D / 4;           // 1024 f32x4 per (b,m) row
constexpr int ROWS_PER_CB = 4;                    // 64 KB per copy block
constexpr int COPY_BLOCKS = B * M / ROWS_PER_CB;  // 1088 (exact)
constexpr int EPARTS      = 2;                    // e-dimension split of hs
constexpr int HS_BLOCKS   = B * HH * 2 * EPARTS;  // 512
constexpr int Y_BLOCKS    = B * HH * 8;           // 1024
constexpr int RED_BLOCKS  = 256;                  // H/S reduce blocks

__device__ __forceinline__ void ring_params(const int* wp_p, const int* valid_p,
                                            int& wp, int& num_excess, int& pos) {
    wp = *wp_p;
    int valid = *valid_p;
    if (valid + C <= M) {
        num_excess = 0;
        pos = (wp + valid) % M;
    } else {
        num_excess = valid + C - M;
        pos = (wp + num_excess) % M;
    }
}

// ---------------------------------------------------------------------------
// One copy block = ROWS_PER_CB (b,m)-rows of one (B,M,HH,128) tensor.
// ---------------------------------------------------------------------------
__device__ __forceinline__ void ring_copy_block(int cb, int tid,
                                                const f32x4* __restrict__ src,
                                                const f32x4* __restrict__ chk,
                                                f32x4* __restrict__ dst,
                                                int pos) {
    int bm0 = cb * ROWS_PER_CB;
#pragma unroll
    for (int r = 0; r < ROWS_PER_CB; ++r) {
        int bm = bm0 + r;
        int m = bm % M;
        int b = bm / M;
        int off = m - pos;
        if (off < 0) off += M;
        const f32x4* s = (off < C) ? &chk[(b * C + off) * INNER4]
                                   : &src[bm * INNER4];
        f32x4* d = &dst[bm * INNER4];
#pragma unroll
        for (int k = 0; k < INNER4 / 256; ++k)
            d[k * 256 + tid] = s[k * 256 + tid];
    }
}

// ---------------------------------------------------------------------------
// hs partial body: block bx in [0,512) -> (epart, fhalf, bh).
// Computes partial sum_{e in chunk} fk (x) v over a 64(f) x 128(d) tile and
// writes the PARTIAL to ws.  R4-proven pipeline: ESTEP=16, SINGLE LDS buffer
// (13 KB total -> thread-cap 8 blocks/CU, LDS not binding), depth-1 register
// prefetch (load t+1 during compute t, store after barrier).
// ---------------------------------------------------------------------------
constexpr int ESTEP = 16;

__device__ void hs_partial_body(int bx,
                                const float* __restrict__ FKi,
                                const float* __restrict__ Vi,
                                float* __restrict__ wsH,
                                float* __restrict__ wsS,
                                int wp, int num_excess) {
    const int tid = threadIdx.x;
    const int epart = bx & (EPARTS - 1);
    int rest = bx >> 1;
    const int fhalf = rest & 1;
    const int bh = rest >> 1;
    const int h = bh & (HH - 1);
    const int b = bh >> 5;
    const int fbase = fhalf * 64;

    const int echunk = (num_excess + EPARTS * ESTEP - 1) / (EPARTS * ESTEP) * ESTEP;
    const int e_lo = epart * echunk;
    const int e_hi_raw = e_lo + echunk;
    const int e_hi = (e_hi_raw < num_excess) ? e_hi_raw : num_excess;

    __shared__ float  fk_s[ESTEP][64];   // 4 KB (row 256 B, 16B-aligned)
    __shared__ f32x4  v_s[ESTEP][32];    // 8 KB
    __shared__ float  sred[4][64];       // 1 KB

    const int tf = tid >> 5;   // 0..7  (8 f-rows each)
    const int td = tid & 31;   // 0..31 (d quads)
    const int cq = tid & 63;   // fk column / s column
    const int qq = tid >> 6;   // quarter

    f32x4 acc[8];
#pragma unroll
    for (int i = 0; i < 8; ++i) acc[i] = (f32x4)0.f;
    float s_part = 0.f;

    float fk_r[4];
    f32x4 v_r[2];

    auto load_tile = [&](int e0) {
#pragma unroll
        for (int j = 0; j < 4; ++j) {
            int e = e0 + qq + 4 * j;
            int me = wp + e;
            if (me >= M) me -= M;
            if (me >= M) me -= M;
            float v = 0.f;
            if (e < e_hi) v = FKi[((b * M + me) * HH + h) * F + fbase + cq];
            fk_r[j] = v;
        }
#pragma unroll
        for (int j = 0; j < 2; ++j) {
            int e = e0 + tf + 8 * j;
            int me = wp + e;
            if (me >= M) me -= M;
            if (me >= M) me -= M;
            f32x4 v = (f32x4)0.f;
            if (e < e_hi) v = *(const f32x4*)&Vi[((b * M + me) * HH + h) * D + td * 4];
            v_r[j] = v;
        }
    };
    auto store_tile = [&]() {
#pragma unroll
        for (int j = 0; j < 4; ++j) fk_s[qq + 4 * j][cq] = fk_r[j];
#pragma unroll
        for (int j = 0; j < 2; ++j) v_s[tf + 8 * j][td] = v_r[j];
    };

    if (e_lo < e_hi) {
        load_tile(e_lo);
        store_tile();
        for (int e0 = e_lo; e0 < e_hi; e0 += ESTEP) {
            bool more = (e0 + ESTEP < e_hi);
            if (more) load_tile(e0 + ESTEP);   // loads in flight during compute
            __syncthreads();                   // staged tile visible
#pragma unroll
            for (int ee = 0; ee < ESTEP; ++ee) {
                f32x4 fa = *(const f32x4*)&fk_s[ee][tf * 8];
                f32x4 fb = *(const f32x4*)&fk_s[ee][tf * 8 + 4];
                f32x4 vv = v_s[ee][td];
                acc[0] += fa.x * vv; acc[1] += fa.y * vv;
                acc[2] += fa.z * vv; acc[3] += fa.w * vv;
                acc[4] += fb.x * vv; acc[5] += fb.y * vv;
                acc[6] += fb.z * vv; acc[7] += fb.w * vv;
            }
#pragma unroll
            for (int j = 0; j < 4; ++j) s_part += fk_s[qq * 4 + j][cq];
            __syncthreads();                   // all reads done
            if (more) store_tile();            // waits vmcnt, writes next tile
        }
    }

    // S partial
    sred[qq][cq] = s_part;
    __syncthreads();
    if (tid < 64) {
        wsS[epart * SZ_S + (b * HH + h) * F + fbase + tid] =
            sred[0][tid] + sred[1][tid] + sred[2][tid] + sred[3][tid];
    }

    // H partial
    float* wsHp = wsH + epart * SZ_H;
#pragma unroll
    for (int i = 0; i < 8; ++i) {
        int f = fbase + tf * 8 + i;
        int base = ((b * HH + h) * F + f) * D + td * 4;
        *(f32x4*)&wsHp[base] = acc[i];
    }
}

// ---------------------------------------------------------------------------
// y body: block bx in [0,1024). 64(c) x 128(d) tile, f-step 32.
// Reads final H_new / S_new (produced by the reduce kernel).
// ---------------------------------------------------------------------------
__device__ void compute_y_den_body(int bx,
                                   const float* __restrict__ fq,
                                   const float* __restrict__ Hn,
                                   const float* __restrict__ Sn,
                                   float* __restrict__ ynum,
                                   float* __restrict__ yden) {
    const int tid = threadIdx.x;
    int t0 = bx;
    const int ct = t0 & 7; t0 >>= 3;
    const int h = t0 & (HH - 1);
    const int b = t0 >> 5;
    const int c0 = ct * 64;
    const int bh = b * HH + h;

    __shared__ float  fq_s[32][65];   // [ee][c], padded
    __shared__ f32x4  h_s[32][32];    // [ee][d4]
    __shared__ float  S_s[128];
    __shared__ float  den_s[64][4];

    const int tc = tid >> 5;  // 0..7 (8 c-rows each)
    const int td = tid & 31;  // 0..31 (d quads)
    const int cq = tid & 63;
    const int qq = tid >> 6;

    if (tid < 128) S_s[tid] = Sn[bh * F + tid];

    f32x4 acc[8];
#pragma unroll
    for (int i = 0; i < 8; ++i) acc[i] = (f32x4)0.f;
    float den_part = 0.f;

    for (int f0 = 0; f0 < F; f0 += 32) {
#pragma unroll
        for (int r = 0; r < 8; ++r) {
            int idx = tid + r * 256;
            int cc = idx >> 5, ee = idx & 31;
            fq_s[ee][cc] = fq[((b * C + c0 + cc) * HH + h) * F + f0 + ee];
        }
#pragma unroll
        for (int r = 0; r < 4; ++r) {
            int idx = tid + r * 256;
            int row = idx >> 5, col = idx & 31;
            h_s[row][col] = *(const f32x4*)&Hn[(bh * F + f0 + row) * D + col * 4];
        }
        __syncthreads();
#pragma unroll
        for (int ee = 0; ee < 32; ++ee) {
            f32x4 hv = h_s[ee][td];
#pragma unroll
            for (int i = 0; i < 8; ++i) {
                float q = fq_s[ee][tc * 8 + i];
                acc[i] += q * hv;
            }
        }
#pragma unroll
        for (int j = 0; j < 8; ++j)
            den_part += fq_s[qq * 8 + j][cq] * S_s[f0 + qq * 8 + j];
        __syncthreads();
    }

    den_s[cq][qq] = den_part;
    __syncthreads();
    if (tid < 64)
        yden[(b * C + c0 + tid) * HH + h] =
            den_s[tid][0] + den_s[tid][1] + den_s[tid][2] + den_s[tid][3];

#pragma unroll
    for (int i = 0; i < 8; ++i) {
        int c = c0 + tc * 8 + i;
        int base = ((b * C + c) * HH + h) * D + td * 4;
        *(f32x4*)&ynum[base] = acc[i];
    }
}

// ---------------------------------------------------------------------------
// Kernel 1: hs partials (blocks 0..511, 13 KB LDS) + V copy + FK copy.
// 512 hs blocks = 2/CU dispatch footprint; copies keep ~6 blocks/CU of TLP.
// ---------------------------------------------------------------------------
__global__ __launch_bounds__(256) void fused_hs_vfk(
        const float* __restrict__ FKi, const float* __restrict__ Vi,
        float* __restrict__ wsH,       float* __restrict__ wsS,
        const f32x4* __restrict__ V4,  const f32x4* __restrict__ vc,  f32x4* __restrict__ oV,
        const f32x4* __restrict__ FK4, const f32x4* __restrict__ fkc, f32x4* __restrict__ oFK,
        const int* __restrict__ wp_p,  const int* __restrict__ valid_p) {
    int wp, num_excess, pos;
    ring_params(wp_p, valid_p, wp, num_excess, pos);

    int bx = blockIdx.x;
    if (bx < HS_BLOCKS) {
        hs_partial_body(bx, FKi, Vi, wsH, wsS, wp, num_excess);
        return;
    }
    bx -= HS_BLOCKS;
    if (bx < COPY_BLOCKS) {
        ring_copy_block(bx, threadIdx.x, V4, vc, oV, pos);
        return;
    }
    bx -= COPY_BLOCKS;
    ring_copy_block(bx, threadIdx.x, FK4, fkc, oFK, pos);
}

// ---------------------------------------------------------------------------
// Kernel 2: tiny reduce: o_H = H_in + wsH0 + wsH1 ; o_S likewise. ~50 MB.
// ---------------------------------------------------------------------------
__global__ __launch_bounds__(256) void red_kernel(
        const float* __restrict__ Hi,  const float* __restrict__ Si,
        const float* __restrict__ wsH, const float* __restrict__ wsS,
        float* __restrict__ Ho,        float* __restrict__ So) {
    const int bx = blockIdx.x;
    const int tid = threadIdx.x;
    constexpr int H4 = SZ_H / 4;              // 524288 f32x4
    const f32x4* h4 = (const f32x4*)Hi;
    const f32x4* w4 = (const f32x4*)wsH;
    f32x4* o4 = (f32x4*)Ho;
    int base = bx * (H4 / RED_BLOCKS) + tid;  // 2048 f32x4 per block
#pragma unroll
    for (int r = 0; r < H4 / RED_BLOCKS / 256; ++r) {  // 8
        int i = base + r * 256;
        f32x4 v = h4[i] + w4[i] + w4[H4 + i];
        o4[i] = v;
    }
    if (bx < SZ_S / 256) {                    // 64 blocks cover S
        int si = bx * 256 + tid;
        So[si] = Si[si] + wsS[si] + wsS[SZ_S + si];
    }
}

// ---------------------------------------------------------------------------
// Kernel 3: y (blocks 0..1023) + K copy.
// ---------------------------------------------------------------------------
__global__ __launch_bounds__(256) void fused_y_k(
        const float* __restrict__ fq, const float* __restrict__ Hn,
        const float* __restrict__ Sn,
        float* __restrict__ ynum,     float* __restrict__ yden,
        const f32x4* __restrict__ K4, const f32x4* __restrict__ kc,
        f32x4* __restrict__ oK,
        const int* __restrict__ wp_p, const int* __restrict__ valid_p) {
    int wp, num_excess, pos;
    ring_params(wp_p, valid_p, wp, num_excess, pos);

    int bx = blockIdx.x;
    if (bx < Y_BLOCKS) {
        compute_y_den_body(bx, fq, Hn, Sn, ynum, yden);
        return;
    }
    bx -= Y_BLOCKS;
    ring_copy_block(bx, threadIdx.x, K4, kc, oK, pos);
}

// ---------------------------------------------------------------------------
extern "C" void kernel_launch(void* const* d_in, const int* in_sizes, int n_in,
                              void* d_out, int out_size, void* d_ws, size_t ws_size,
                              hipStream_t stream) {
    const float* K   = (const float*)d_in[0];
    const float* V   = (const float*)d_in[1];
    const float* FK  = (const float*)d_in[2];
    const float* H   = (const float*)d_in[3];
    const float* S   = (const float*)d_in[4];
    const float* k_c = (const float*)d_in[5];
    const float* v_c = (const float*)d_in[6];
    const float* fk_c= (const float*)d_in[7];
    const float* fq  = (const float*)d_in[8];
    const int* wp    = (const int*)d_in[9];
    const int* valid = (const int*)d_in[10];

    float* out = (float*)d_out;
    float* o_ynum = out + OFF_YNUM;
    float* o_yden = out + OFF_YDEN;
    float* o_K    = out + OFF_K;
    float* o_V    = out + OFF_V;
    float* o_FK   = out + OFF_FK;
    float* o_H    = out + OFF_H;
    float* o_S    = out + OFF_S;

    float* wsH = (float*)d_ws;              // 2 x SZ_H floats (16.8 MB)
    float* wsS = wsH + EPARTS * SZ_H;       // 2 x SZ_S floats (0.13 MB)

    // Kernel 1: hs partials overlapped with V, FK ring copies.
    fused_hs_vfk<<<HS_BLOCKS + 2 * COPY_BLOCKS, 256, 0, stream>>>(
        FK, V, wsH, wsS,
        (const f32x4*)V,  (const f32x4*)v_c,  (f32x4*)o_V,
        (const f32x4*)FK, (const f32x4*)fk_c, (f32x4*)o_FK,
        wp, valid);

    // Kernel 2: tiny H/S reduce (partials are L3-hot).
    red_kernel<<<RED_BLOCKS, 256, 0, stream>>>(H, S, wsH, wsS, o_H, o_S);

    // Kernel 3: y_num/y_den overlapped with K ring copy.
    fused_y_k<<<Y_BLOCKS + COPY_BLOCKS, 256, 0, stream>>>(
        fq, o_H, o_S, o_ynum, o_yden,
        (const f32x4*)K, (const f32x4*)k_c, (f32x4*)o_K,
        wp, valid);
}

// Round 13
// 143.077 us; speedup vs baseline: 1.1433x; 1.0271x over previous
//
#include <hip/hip_runtime.h>

typedef float f32x4 __attribute__((ext_vector_type(4)));

// Problem constants (from reference setup_inputs)
constexpr int B  = 4;
constexpr int M  = 1088;
constexpr int HH = 32;
constexpr int D  = 128;
constexpr int F  = 128;
constexpr int C  = 512;

constexpr int SZ_YNUM = B * C * HH * D;   // 8388608
constexpr int SZ_YDEN = B * C * HH;       // 65536
constexpr int SZ_KVM  = B * M * HH * D;   // 17825792
constexpr int SZ_H    = B * HH * F * D;   // 2097152
constexpr int SZ_S    = B * HH * F;       // 16384

constexpr int OFF_YNUM = 0;
constexpr int OFF_YDEN = OFF_YNUM + SZ_YNUM;
constexpr int OFF_K    = OFF_YDEN + SZ_YDEN;
constexpr int OFF_V    = OFF_K + SZ_KVM;
constexpr int OFF_FK   = OFF_V + SZ_KVM;
constexpr int OFF_H    = OFF_FK + SZ_KVM;
constexpr int OFF_S    = OFF_H + SZ_H;

constexpr int INNER4      = HH * D / 4;           // 1024 f32x4 per (b,m) row
constexpr int ROWS_PER_CB = 4;                    // 64 KB per copy block
constexpr int COPY_BLOCKS = B * M / ROWS_PER_CB;  // 1088 (exact)
constexpr int HS_BLOCKS   = B * HH * 4;           // 512  (32-f quarters)
constexpr int Y_BLOCKS    = B * HH * 16;          // 2048 (32-c tiles)
constexpr int ESTEP       = 16;

__device__ __forceinline__ void ring_params(const int* wp_p, const int* valid_p,
                                            int& wp, int& num_excess, int& pos) {
    wp = *wp_p;
    int valid = *valid_p;
    if (valid + C <= M) {
        num_excess = 0;
        pos = (wp + valid) % M;
    } else {
        num_excess = valid + C - M;
        pos = (wp + num_excess) % M;
    }
}

// ---------------------------------------------------------------------------
// One copy block = ROWS_PER_CB (b,m)-rows of one (B,M,HH,128) tensor.
// ---------------------------------------------------------------------------
__device__ __forceinline__ void ring_copy_block(int cb, int tid,
                                                const f32x4* __restrict__ src,
                                                const f32x4* __restrict__ chk,
                                                f32x4* __restrict__ dst,
                                                int pos) {
    int bm0 = cb * ROWS_PER_CB;
#pragma unroll
    for (int r = 0; r < ROWS_PER_CB; ++r) {
        int bm = bm0 + r;
        int m = bm % M;
        int b = bm / M;
        int off = m - pos;
        if (off < 0) off += M;
        const f32x4* s = (off < C) ? &chk[(b * C + off) * INNER4]
                                   : &src[bm * INNER4];
        f32x4* d = &dst[bm * INNER4];
#pragma unroll
        for (int k = 0; k < INNER4 / 256; ++k)
            d[k * 256 + tid] = s[k * 256 + tid];
    }
}

// ---------------------------------------------------------------------------
// hs body: block bx in [0,512) -> (fquarter, bh).  32(f) x 128(d) tile of
// H[b,h]; full e-range per block (fquarters are disjoint -> direct o_H write,
// no workspace, no reduce).  acc = 4 x f32x4 = 16 VGPR.  11 KB LDS.
// ---------------------------------------------------------------------------
__device__ void hs_body(int bx,
                        const float* __restrict__ FKi,
                        const float* __restrict__ Vi,
                        const float* __restrict__ Hi,
                        const float* __restrict__ Si,
                        float* __restrict__ Ho,
                        float* __restrict__ So,
                        int wp, int num_excess) {
    const int tid = threadIdx.x;
    const int fq4 = bx & 3;
    const int bh = bx >> 2;
    const int h = bh & (HH - 1);
    const int b = bh >> 5;
    const int fbase = fq4 * 32;

    __shared__ float fk_s[ESTEP][32];   // 2 KB
    __shared__ f32x4 v_s[ESTEP][32];    // 8 KB
    __shared__ float sred[8][32];       // 1 KB

    const int tf = tid >> 5;   // 0..7  (4 f-rows each)
    const int td = tid & 31;   // 0..31 (d quads / staging col)

    f32x4 acc[4];
#pragma unroll
    for (int i = 0; i < 4; ++i) acc[i] = (f32x4)0.f;
    float s_part = 0.f;

    float fk_r[2];
    f32x4 v_r[2];

    auto load_tile = [&](int e0) {
#pragma unroll
        for (int r = 0; r < 2; ++r) {
            int row = tf + r * 8;
            int e = e0 + row;
            int me = wp + e;
            if (me >= M) me -= M;
            if (me >= M) me -= M;
            float fv = 0.f;
            f32x4 vv = (f32x4)0.f;
            if (e < num_excess) {
                int rowbase = (b * M + me) * HH + h;
                fv = FKi[rowbase * F + fbase + td];
                vv = *(const f32x4*)&Vi[rowbase * D + td * 4];
            }
            fk_r[r] = fv;
            v_r[r] = vv;
        }
    };
    auto store_tile = [&]() {
#pragma unroll
        for (int r = 0; r < 2; ++r) {
            fk_s[tf + r * 8][td] = fk_r[r];
            v_s[tf + r * 8][td] = v_r[r];
        }
    };

    if (num_excess > 0) {
        load_tile(0);
        store_tile();
        for (int e0 = 0; e0 < num_excess; e0 += ESTEP) {
            bool more = (e0 + ESTEP < num_excess);
            if (more) load_tile(e0 + ESTEP);   // loads in flight during compute
            __syncthreads();                   // staged tile visible
#pragma unroll
            for (int ee = 0; ee < ESTEP; ++ee) {
                f32x4 fa = *(const f32x4*)&fk_s[ee][tf * 4];
                f32x4 vv = v_s[ee][td];
                acc[0] += fa.x * vv;
                acc[1] += fa.y * vv;
                acc[2] += fa.z * vv;
                acc[3] += fa.w * vv;
            }
            // S partial: thread (tf,td) covers rows 2*tf, 2*tf+1, col td
            s_part += fk_s[tf * 2][td] + fk_s[tf * 2 + 1][td];
            __syncthreads();                   // all reads done
            if (more) store_tile();            // waits vmcnt, writes next tile
        }
    }

    // S_new (quarter columns are exclusive to this block)
    sred[tf][td] = s_part;
    __syncthreads();
    if (tid < 32) {
        int si = bh * F + fbase + tid;
        float s = Si[si];
#pragma unroll
        for (int g = 0; g < 8; ++g) s += sred[g][tid];
        So[si] = s;
    }

    // H_new = H_old + acc (rows exclusive to this block)
#pragma unroll
    for (int i = 0; i < 4; ++i) {
        int f = fbase + tf * 4 + i;
        int base = (bh * F + f) * D + td * 4;
        f32x4 hold = *(const f32x4*)&Hi[base];
        *(f32x4*)&Ho[base] = hold + acc[i];
    }
}

// ---------------------------------------------------------------------------
// y body: block bx in [0,2048) -> (ctile, bh). 32(c) x 128(d) tile, f-step 32.
// acc = 4 x f32x4 = 16 VGPR.  ~22 KB LDS.
// ---------------------------------------------------------------------------
__device__ void y_body(int bx,
                       const float* __restrict__ fq,
                       const float* __restrict__ Hn,
                       const float* __restrict__ Sn,
                       float* __restrict__ ynum,
                       float* __restrict__ yden) {
    const int tid = threadIdx.x;
    const int ct = bx & 15;
    const int bh = bx >> 4;
    const int h = bh & (HH - 1);
    const int b = bh >> 5;
    const int c0 = ct * 32;

    __shared__ float fq_s[32][33];   // [f][c], padded (4.2 KB)
    __shared__ f32x4 h_s[32][32];    // [f][d4]         (16 KB)
    __shared__ float S_s[128];
    __shared__ float den_s[32][8];   // 1 KB

    const int tc = tid >> 5;  // 0..7 (4 c-rows each)
    const int td = tid & 31;  // 0..31 (d quads)
    const int cq = tid & 31;  // den: c-row
    const int qq = tid >> 5;  // den: f sub-group (4 f each)

    if (tid < 128) S_s[tid] = Sn[bh * F + tid];

    f32x4 acc[4];
#pragma unroll
    for (int i = 0; i < 4; ++i) acc[i] = (f32x4)0.f;
    float den_part = 0.f;

    for (int f0 = 0; f0 < F; f0 += 32) {
        // fq tile: 32 c x 32 f transposed into [f][c]; 4 loads/thread
#pragma unroll
        for (int r = 0; r < 4; ++r) {
            int idx = tid + r * 256;
            int cc = idx >> 5, ee = idx & 31;
            fq_s[ee][cc] = fq[((b * C + c0 + cc) * HH + h) * F + f0 + ee];
        }
        // H tile: 32 f x 128 d as f32x4; 4 loads/thread
#pragma unroll
        for (int r = 0; r < 4; ++r) {
            int idx = tid + r * 256;
            int row = idx >> 5, col = idx & 31;
            h_s[row][col] = *(const f32x4*)&Hn[(bh * F + f0 + row) * D + col * 4];
        }
        __syncthreads();
#pragma unroll
        for (int ee = 0; ee < 32; ++ee) {
            f32x4 hv = h_s[ee][td];
#pragma unroll
            for (int i = 0; i < 4; ++i) {
                float q = fq_s[ee][tc * 4 + i];
                acc[i] += q * hv;
            }
        }
#pragma unroll
        for (int j = 0; j < 4; ++j)
            den_part += fq_s[qq * 4 + j][cq] * S_s[f0 + qq * 4 + j];
        __syncthreads();
    }

    den_s[cq][qq] = den_part;
    __syncthreads();
    if (tid < 32) {
        float d = 0.f;
#pragma unroll
        for (int g = 0; g < 8; ++g) d += den_s[tid][g];
        yden[(b * C + c0 + tid) * HH + h] = d;
    }

#pragma unroll
    for (int i = 0; i < 4; ++i) {
        int c = c0 + tc * 4 + i;
        int base = ((b * C + c) * HH + h) * D + td * 4;
        *(f32x4*)&ynum[base] = acc[i];
    }
}

// ---------------------------------------------------------------------------
// Kernel 1: hs (blocks 0..511, writes o_H/o_S directly) + V copy + FK copy.
// Forced 8 blocks/CU so copy waves keep HBM saturated.
// ---------------------------------------------------------------------------
__global__ __launch_bounds__(256, 8) void fused_hs_vfk(
        const float* __restrict__ FKi, const float* __restrict__ Vi,
        const float* __restrict__ Hi,  const float* __restrict__ Si,
        float* __restrict__ Ho,        float* __restrict__ So,
        const f32x4* __restrict__ V4,  const f32x4* __restrict__ vc,  f32x4* __restrict__ oV,
        const f32x4* __restrict__ FK4, const f32x4* __restrict__ fkc, f32x4* __restrict__ oFK,
        const int* __restrict__ wp_p,  const int* __restrict__ valid_p) {
    int wp, num_excess, pos;
    ring_params(wp_p, valid_p, wp, num_excess, pos);

    int bx = blockIdx.x;
    if (bx < HS_BLOCKS) {
        hs_body(bx, FKi, Vi, Hi, Si, Ho, So, wp, num_excess);
        return;
    }
    bx -= HS_BLOCKS;
    if (bx < COPY_BLOCKS) {
        ring_copy_block(bx, threadIdx.x, V4, vc, oV, pos);
        return;
    }
    bx -= COPY_BLOCKS;
    ring_copy_block(bx, threadIdx.x, FK4, fkc, oFK, pos);
}

// ---------------------------------------------------------------------------
// Kernel 2: K copy (blocks 0..1087, dispatched first) + y (2048 blocks).
// ---------------------------------------------------------------------------
__global__ __launch_bounds__(256, 8) void fused_k_y(
        const float* __restrict__ fq, const float* __restrict__ Hn,
        const float* __restrict__ Sn,
        float* __restrict__ ynum,     float* __restrict__ yden,
        const f32x4* __restrict__ K4, const f32x4* __restrict__ kc,
        f32x4* __restrict__ oK,
        const int* __restrict__ wp_p, const int* __restrict__ valid_p) {
    int wp, num_excess, pos;
    ring_params(wp_p, valid_p, wp, num_excess, pos);

    int bx = blockIdx.x;
    if (bx < COPY_BLOCKS) {
        ring_copy_block(bx, threadIdx.x, K4, kc, oK, pos);
        return;
    }
    bx -= COPY_BLOCKS;
    y_body(bx, fq, Hn, Sn, ynum, yden);
}

// ---------------------------------------------------------------------------
extern "C" void kernel_launch(void* const* d_in, const int* in_sizes, int n_in,
                              void* d_out, int out_size, void* d_ws, size_t ws_size,
                              hipStream_t stream) {
    const float* K   = (const float*)d_in[0];
    const float* V   = (const float*)d_in[1];
    const float* FK  = (const float*)d_in[2];
    const float* H   = (const float*)d_in[3];
    const float* S   = (const float*)d_in[4];
    const float* k_c = (const float*)d_in[5];
    const float* v_c = (const float*)d_in[6];
    const float* fk_c= (const float*)d_in[7];
    const float* fq  = (const float*)d_in[8];
    const int* wp    = (const int*)d_in[9];
    const int* valid = (const int*)d_in[10];

    float* out = (float*)d_out;
    float* o_ynum = out + OFF_YNUM;
    float* o_yden = out + OFF_YDEN;
    float* o_K    = out + OFF_K;
    float* o_V    = out + OFF_V;
    float* o_FK   = out + OFF_FK;
    float* o_H    = out + OFF_H;
    float* o_S    = out + OFF_S;

    // Kernel 1: H/S update (direct write) overlapped with V, FK ring copies.
    fused_hs_vfk<<<HS_BLOCKS + 2 * COPY_BLOCKS, 256, 0, stream>>>(
        FK, V, H, S, o_H, o_S,
        (const f32x4*)V,  (const f32x4*)v_c,  (f32x4*)o_V,
        (const f32x4*)FK, (const f32x4*)fk_c, (f32x4*)o_FK,
        wp, valid);

    // Kernel 2: K ring copy (first) overlapped with y_num/y_den.
    fused_k_y<<<COPY_BLOCKS + Y_BLOCKS, 256, 0, stream>>>(
        fq, o_H, o_S, o_ynum, o_yden,
        (const f32x4*)K, (const f32x4*)k_c, (f32x4*)o_K,
        wp, valid);
}